// Round 1
// baseline (184.949 us; speedup 1.0000x reference)
//
#include <hip/hip_runtime.h>
#include <cstdint>
#include <cstddef>

#define NBINS 32768         // 15-bit histogram of orderable score (u >> 17)
#define FINB 64u            // bin >= 64 <=> finite score (15-bit space)
#define CAP_C 2048          // candidate pool (pow2, = sort size)
#define NW (CAP_C / 64)     // 64-bit mask words per row = 32
#define WP (NW + 2)         // padded LDS row stride = 34 (even: 16B row align for b128)
#define TARGET 1792u        // threshold target (headroom to CAP_C)
#define KMAX 1008           // kept-list capacity
#define MROWS 16            // rows per mask block
#define HB 1024             // hist block threads
#define HE 32768            // keys per hist block (16-bit pack: counts <= HE < 65536)
#define CNT_STRIDE 64       // cnt[b*64]: 256B per counter, no shared lines
#define ARRIVE_OFF 16       // arrive counter at cnt[b*64+16] (same line, time-separated)
#define CPB 64              // compact blocks per batch

typedef unsigned long long u64;

__device__ __forceinline__ unsigned orderable(float f) {
  unsigned b = __float_as_uint(f);
  return (b & 0x80000000u) ? ~b : (b | 0x80000000u);
}

__device__ __forceinline__ u64 shfl_xor_u64(u64 v, int m) {
  int lo = __shfl_xor((int)(unsigned)(v & 0xFFFFFFFFull), m, 64);
  int hi = __shfl_xor((int)(unsigned)(v >> 32), m, 64);
  return ((u64)(unsigned)hi << 32) | (u64)(unsigned)lo;
}

// Pure streaming: computes keys only (boxes re-decoded later for the 2048
// winners). Also zero-fills hist + cnt/arrive lines (no separate init).
__global__ void decode_kernel(const float4* __restrict__ anchors,
                              const float4* __restrict__ deltas,
                              const float* __restrict__ obj,
                              const int* __restrict__ im_h_p,
                              const int* __restrict__ im_w_p,
                              unsigned* __restrict__ keys,
                              unsigned* __restrict__ hist,
                              unsigned* __restrict__ cnt,
                              int N, int B) {
#pragma clang fp contract(off)
  int n = blockIdx.x * blockDim.x + threadIdx.x;
  int stride = gridDim.x * blockDim.x;
  for (int j = n; j < B * NBINS; j += stride) hist[j] = 0u;
  for (int j = n; j < B * CNT_STRIDE; j += stride) cnt[j] = 0u;
  if (n >= N) return;
  float imw = (float)(*im_w_p);
  float imh = (float)(*im_h_p);
  float4 a = anchors[n];
  float aw = a.z - a.x;
  float ah = a.w - a.y;
  float acx = a.x + 0.5f * aw;
  float acy = a.y + 0.5f * ah;
  const float LOGM = 4.135166556742356f;  // log(1000/16) rounded to f32
  for (int b = 0; b < B; ++b) {
    size_t off = (size_t)b * N + n;
    float4 d = deltas[off];
    float dw = fminf(d.z, LOGM), dh = fminf(d.w, LOGM);
    float pcx = d.x * aw + acx;
    float pcy = d.y * ah + acy;
    float pw = expf(dw) * aw;
    float ph = expf(dh) * ah;
    float x1 = fminf(fmaxf(pcx - 0.5f * pw, 0.0f), imw);
    float y1 = fminf(fmaxf(pcy - 0.5f * ph, 0.0f), imh);
    float x2 = fminf(fmaxf(pcx + 0.5f * pw, 0.0f), imw);
    float y2 = fminf(fmaxf(pcy + 0.5f * ph, 0.0f), imh);
    float area = (x2 - x1) * (y2 - y1);
    float sc = (area > 1.0f) ? obj[off] : -__builtin_inff();
    keys[off] = orderable(sc);
  }
}

// LDS-privatized histogram, single pass + FUSED threshold: the last-arriving
// block per batch (device-scope arrive counter) computes T_lo in-kernel,
// removing the separate 4-block threshold dispatch from the critical chain.
__global__ void __launch_bounds__(HB) hist_kernel(const unsigned* __restrict__ keys,
                                                  unsigned* __restrict__ hist,
                                                  unsigned* __restrict__ T_lo,
                                                  unsigned* __restrict__ cnt,
                                                  int N) {
  __shared__ unsigned hl[NBINS / 2];  // 16384 uints = 64 KB (reused as scan scratch)
  int t = threadIdx.x, b = blockIdx.y;
  for (int i = t; i < NBINS / 2; i += HB) hl[i] = 0u;
  __syncthreads();
  const uint4* kb = (const uint4*)(keys + (size_t)b * N) + (size_t)blockIdx.x * (HE / 4);
  int lim = HE / 4;
  int rem4 = (N - blockIdx.x * HE) / 4;
  if (lim > rem4) lim = rem4;
  for (int i = t; i < lim; i += HB) {
    uint4 v = kb[i];
    unsigned b0 = v.x >> 17, b1 = v.y >> 17, b2 = v.z >> 17, b3 = v.w >> 17;
    atomicAdd(&hl[b0 >> 1], (b0 & 1u) ? 65536u : 1u);
    atomicAdd(&hl[b1 >> 1], (b1 & 1u) ? 65536u : 1u);
    atomicAdd(&hl[b2 >> 1], (b2 & 1u) ? 65536u : 1u);
    atomicAdd(&hl[b3 >> 1], (b3 & 1u) ? 65536u : 1u);
  }
  __syncthreads();
  unsigned* hg = hist + (size_t)b * NBINS;
  for (int i = t; i < NBINS / 2; i += HB) {
    unsigned v = hl[i];
    unsigned clo = v & 0xFFFFu, chi = v >> 16;
    if (clo) atomicAdd(&hg[2 * i], clo);
    if (chi) atomicAdd(&hg[2 * i + 1], chi);
  }
  __syncthreads();  // all flush atomics drained (vmcnt(0) before barrier); hl dead
  if (t == 0) {
    __threadfence();
    unsigned old = atomicAdd(&cnt[b * CNT_STRIDE + ARRIVE_OFF], 1u);
    hl[4096] = (old == gridDim.x - 1u) ? 1u : 0u;
  }
  __syncthreads();
  if (hl[4096] == 0u) return;
  // ---- fused threshold (this block arrived last for batch b) ----
  // device-scope atomic loads: other blocks' flushes are at the coherent point
  const int BPT = NBINS / 1024;  // 32 bins/thread, contiguous ownership
  unsigned mysum = 0;
  for (int k = 0; k < BPT; ++k) {
    unsigned bin = (unsigned)(t * BPT + k);
    if (bin >= FINB)
      mysum += __hip_atomic_load(&hg[bin], __ATOMIC_RELAXED, __HIP_MEMORY_SCOPE_AGENT);
  }
  if (t == 0) hl[2048] = 0xFFFFFFFFu;  // s_T slot
  hl[t] = mysum;                       // s_part = hl[0..1023]
  __syncthreads();
  for (int d = 1; d < 1024; d <<= 1) {  // inclusive suffix sum
    unsigned v = (t + d < 1024) ? hl[t + d] : 0u;
    __syncthreads();
    hl[t] += v;
    __syncthreads();
  }
  unsigned total = hl[0];
  unsigned target = (TARGET < total) ? TARGET : total;
  unsigned above = (t + 1 < 1024) ? hl[t + 1] : 0u;
  if (total > 0u && above < target && hl[t] >= target) {  // unique crossing thread
    unsigned c = above;
    for (int k = BPT - 1; k >= 0; --k) {
      unsigned bin = (unsigned)(t * BPT + k);
      if (bin < FINB) break;
      unsigned hv = __hip_atomic_load(&hg[bin], __ATOMIC_RELAXED, __HIP_MEMORY_SCOPE_AGENT);
      c += hv;
      if (c >= target) {
        unsigned T = bin;
        if (c > CAP_C && (c - hv) > 0u) T = bin + 1u;  // never overflow CAP_C
        hl[2048] = T;
        break;
      }
    }
  }
  __syncthreads();
  if (t == 0) T_lo[b] = (total == 0u) ? 0xFFFFFFFFu : hl[2048];
}

// compact (full-GPU grid, block-aggregated): 256 blocks scan 4 KB of keys
// each, LDS-stage winners, ONE reservation atomic per block, coalesced writes.
__global__ void __launch_bounds__(1024) compact_kernel(const unsigned* __restrict__ keys,
                                                       const unsigned* __restrict__ T_lo,
                                                       u64* __restrict__ cand,
                                                       unsigned* __restrict__ cnt, int N) {
  __shared__ u64 s_w[4096];  // 32 KB winner staging (total/batch <= ~2048)
  __shared__ unsigned s_n, s_base;
  int b = blockIdx.y, t = threadIdx.x;
  if (t == 0) s_n = 0u;
  __syncthreads();
  unsigned T = T_lo[b];
  int slice4 = N / 4 / CPB;  // uint4s per block (N=262144: 1024 -> 1/thread)
  const uint4* k4 = (const uint4*)(keys + (size_t)b * N) + (size_t)blockIdx.x * slice4;
  for (int i = t; i < slice4; i += 1024) {
    uint4 v = k4[i];
    int bi = (blockIdx.x * slice4 + i) * 4;
    if ((v.x >> 17) >= T) { unsigned p = atomicAdd(&s_n, 1u); if (p < 4096u) s_w[p] = ((u64)v.x << 32) | (unsigned)(~(bi + 0)); }
    if ((v.y >> 17) >= T) { unsigned p = atomicAdd(&s_n, 1u); if (p < 4096u) s_w[p] = ((u64)v.y << 32) | (unsigned)(~(bi + 1)); }
    if ((v.z >> 17) >= T) { unsigned p = atomicAdd(&s_n, 1u); if (p < 4096u) s_w[p] = ((u64)v.z << 32) | (unsigned)(~(bi + 2)); }
    if ((v.w >> 17) >= T) { unsigned p = atomicAdd(&s_n, 1u); if (p < 4096u) s_w[p] = ((u64)v.w << 32) | (unsigned)(~(bi + 3)); }
  }
  __syncthreads();
  unsigned n = s_n < 4096u ? s_n : 4096u;
  if (t == 0) s_base = (n > 0u) ? atomicAdd(&cnt[b * CNT_STRIDE], n) : 0u;
  __syncthreads();
  unsigned gb = s_base;
  for (unsigned j = t; j < n; j += 1024) {
    unsigned p = gb + j;
    if (p < CAP_C) cand[(size_t)b * CAP_C + p] = s_w[j];
  }
}

// One block per batch: bitonic sort CAP_C keys descending, then gather sorted
// boxes by RE-DECODING the winners (saves the full B*N*16B boxes store in
// decode; identical fp-contract-off arithmetic -> bit-exact).
__global__ void __launch_bounds__(1024) sort_kernel(const u64* __restrict__ cand,
                                                    const unsigned* __restrict__ cntp,
                                                    const float4* __restrict__ anchors,
                                                    const float4* __restrict__ deltas,
                                                    const int* __restrict__ im_h_p,
                                                    const int* __restrict__ im_w_p,
                                                    float4* __restrict__ sboxes,
                                                    float* __restrict__ sscore,
                                                    int N) {
#pragma clang fp contract(off)
  __shared__ u64 sk[CAP_C];  // 16 KB
  int b = blockIdx.x, t = threadIdx.x;
  int cnt = (int)cntp[b * CNT_STRIDE];
  if (cnt > CAP_C) cnt = CAP_C;
  for (int i = t; i < CAP_C; i += 1024)
    sk[i] = (i < cnt) ? cand[(size_t)b * CAP_C + i] : 0ull;  // pad sinks to end
  __syncthreads();
  for (unsigned kk = 2; kk <= CAP_C; kk <<= 1) {
    for (unsigned j = kk >> 1; j >= 1u; j >>= 1) {
      if (j >= 64u) __syncthreads();  // inter-wave phases only
      unsigned pid = (unsigned)t;     // exactly CAP_C/2 pairs
      unsigned i = ((pid & ~(j - 1u)) << 1) | (pid & (j - 1u));
      unsigned p = i | j;
      u64 va = sk[i], vb = sk[p];
      bool up = ((i & kk) == 0u);
      bool sw = up ? (va < vb) : (va > vb);
      if (sw) { sk[i] = vb; sk[p] = va; }
    }
  }
  __syncthreads();
  float imw = (float)(*im_w_p);
  float imh = (float)(*im_h_p);
  const float LOGM = 4.135166556742356f;
  for (int i = t; i < CAP_C; i += 1024) {
    u64 key = sk[i];
    float4 bx = make_float4(0.f, 0.f, 0.f, 0.f);
    float sc = -__builtin_inff();
    if (i < cnt) {
      unsigned idx = ~(unsigned)(key & 0xFFFFFFFFull);
      float4 a = anchors[idx];
      float4 d = deltas[(size_t)b * N + idx];
      float aw = a.z - a.x;
      float ah = a.w - a.y;
      float acx = a.x + 0.5f * aw;
      float acy = a.y + 0.5f * ah;
      float dw = fminf(d.z, LOGM), dh = fminf(d.w, LOGM);
      float pcx = d.x * aw + acx;
      float pcy = d.y * ah + acy;
      float pw = expf(dw) * aw;
      float ph = expf(dh) * ah;
      bx.x = fminf(fmaxf(pcx - 0.5f * pw, 0.0f), imw);
      bx.y = fminf(fmaxf(pcy - 0.5f * ph, 0.0f), imh);
      bx.z = fminf(fmaxf(pcx + 0.5f * pw, 0.0f), imw);
      bx.w = fminf(fmaxf(pcy + 0.5f * ph, 0.0f), imh);
      unsigned u = (unsigned)(key >> 32);
      unsigned sb2 = (u & 0x80000000u) ? (u ^ 0x80000000u) : ~u;
      sc = __uint_as_float(sb2);
    }
    sboxes[(size_t)b * CAP_C + i] = bx;
    sscore[(size_t)b * CAP_C + i] = sc;
  }
}

// Pairwise suppression masks — UPPER TRIANGLE ONLY (chunk >= row>>6): walk
// never consumes removed-word w after tile w, so lower-triangle words are
// dead (their garbage only lands in already-consumed removed words).
__global__ void __launch_bounds__(256) mask_kernel(const float4* __restrict__ sboxes,
                                                   u64* __restrict__ mask) {
#pragma clang fp contract(off)
  __shared__ float4 sb[CAP_C];  // 32 KB
  int b = blockIdx.y, t = threadIdx.x;
  int wave = t >> 6, lane = t & 63;
  const float4* src = sboxes + (size_t)b * CAP_C;
  for (int i = t; i < CAP_C; i += 256) sb[i] = src[i];
  __syncthreads();
  for (int r = 0; r < MROWS; ++r) {
    int row = blockIdx.x * MROWS + r;
    int c0 = row >> 6;                         // first live chunk (diag block)
    float4 rb = sb[row];                       // broadcast read
    float ra = (rb.z - rb.x) * (rb.w - rb.y);  // picked-box area (barea)
    for (int chunk = wave; chunk < NW; chunk += 4) {
      if (chunk < c0) continue;                // wave-uniform skip (dead words)
      float4 cb = sb[chunk * 64 + lane];
      float ix1 = fmaxf(rb.x, cb.x), iy1 = fmaxf(rb.y, cb.y);
      float ix2 = fminf(rb.z, cb.z), iy2 = fminf(rb.w, cb.w);
      float inter = fmaxf(ix2 - ix1, 0.0f) * fmaxf(iy2 - iy1, 0.0f);
      float ca = (cb.z - cb.x) * (cb.w - cb.y);
      float iou = inter / (ra + ca - inter + 1e-9f);
      u64 bal = __ballot(iou > 0.7f);
      if (lane == 0)
        mask[((size_t)b * CAP_C + row) * NW + chunk] = bal;
    }
  }
}

// ---- Walk v8: producer/consumer pipeline + b128 apply.
// WP=34 keeps every LDS row 16B-aligned (272 = 16*17) so the apply reads a
// word-PAIR per lane via ds_read_b128 (bank-optimal: 8 accesses/bank = b128
// floor), each lane owning a 16-row group; 2-step shfl_xor OR-reduction merges
// groups. removed state = per-lane word pair (x4 dup). 16 b128 reads/tile vs
// the old 64 b64 (2-way dup).
__global__ void __launch_bounds__(256, 1) walk_kernel(const u64* __restrict__ mask,
                                                      const float4* __restrict__ sboxes,
                                                      const float* __restrict__ sscore,
                                                      const unsigned* __restrict__ cntp,
                                                      float* __restrict__ out, int K) {
  __shared__ u64 s_buf[2][64 * WP];   // 2 x 17 KB staged tiles
  __shared__ int s_keep[KMAX];
  __shared__ int s_ctl[4];            // [tt&1]: stop flag, [2]: nk
  const int b = blockIdx.x;
  const int t = threadIdx.x;
  const int wave = t >> 6, lane = t & 63;
  const u64* M = mask + (size_t)b * CAP_C * NW;
  int cnt = (int)cntp[b * CNT_STRIDE];
  if (cnt > CAP_C) cnt = CAP_C;
  const u64 lane_above = (lane == 63) ? 0ull : (~0ull << (lane + 1));

  // prologue: all 256 threads stage tile 0 (2048 u64, coalesced)
  for (int k = 0; k < 8; ++k) {
    int e = k * 256 + t;
    s_buf[0][(e >> 5) * WP + (e & 31)] = M[e];
  }
  if (t == 0) { s_ctl[0] = 0; s_ctl[1] = 0; s_ctl[2] = 0; }
  __syncthreads();

  u64 rm0 = 0ull, rm1 = 0ull;  // removed words (2p, 2p+1), p = lane&15, dup x4
  int nk = 0;                  // wave0-maintained keep count
  int base = 0;
  int cur = 0;
  const int pr = (lane & 15) * 2;  // word index of this lane's pair
  const int grp = lane >> 4;       // 16-row group owned in apply

  for (int tt = 0; tt < CAP_C / 64; ++tt) {
    int par = tt & 1;
    if (wave != 0) {
      // ---- producer: stage tile tt+1 into the spare buffer
      int nt = base + 64;
      if (nt > CAP_C - 64) nt = CAP_C - 64;   // clamp: full tile stays in-bounds
      const u64* src = M + (size_t)nt * NW;
      u64* dst = s_buf[cur ^ 1];
      int s = t - 64;                          // 0..191
      for (int k = 0; k < 11; ++k) {
        int e = k * 192 + s;
        if (e < 64 * NW)
          dst[(e >> 5) * WP + (e & 31)] = src[e];
      }
    } else {
      // ---- consumer (wave 0): resolve tile tt from staged buffer
      const u64* buf = s_buf[cur];
      int tw = base >> 6;                      // 0..31
      u64 D = buf[(size_t)lane * WP + tw];     // lane j = row j's tile-diag word
      u64 rmw = (tw & 1) ? rm1 : rm0;          // uniform pair-half select
      unsigned rlo = __builtin_amdgcn_readlane((unsigned)(rmw & 0xFFFFFFFFull), tw >> 1);
      unsigned rhi = __builtin_amdgcn_readlane((unsigned)(rmw >> 32), tw >> 1);
      u64 in_rm = ((u64)rhi << 32) | (u64)rlo;
      int rem = cnt - base;
      u64 valid = (rem >= 64) ? ~0ull : ((rem <= 0) ? 0ull : ((1ull << rem) - 1ull));
      u64 pend = (~in_rm) & valid;
      u64 keep = 0ull;
      while (pend != 0ull) {                   // O(#suppressing keeps) trips
        bool cond = ((pend >> lane) & 1ull) && ((D & pend & lane_above) != 0ull);
        u64 bal = __ballot((int)cond);
        if (bal == 0ull) { keep |= pend; break; }
        int f = __builtin_ctzll(bal);
        u64 beq = (2ull << f) - 1ull;          // bits <= f (f=63 wraps to ~0)
        keep |= pend & beq;
        unsigned dlo = __builtin_amdgcn_readlane((unsigned)(D & 0xFFFFFFFFull), f);
        unsigned dhi = __builtin_amdgcn_readlane((unsigned)(D >> 32), f);
        u64 rowf = ((u64)dhi << 32) | (u64)dlo;
        pend &= ~beq;
        pend &= ~rowf;
      }
      int cap = K - nk;
      int kc = __popcll(keep);
      if (kc > cap) {                          // exact greedy K-cutoff
        bool mine = ((keep >> lane) & 1ull) &&
                    (__popcll(keep & ((1ull << lane) - 1ull)) < cap);
        keep = __ballot((int)mine);
        kc = cap;
      }
      if ((keep >> lane) & 1ull)
        s_keep[nk + __popcll(keep & ((1ull << lane) - 1ull))] = base + lane;
      nk += kc;
      // ---- apply: 16 x ds_read_b128 (word-pair per lane, 16 rows per group),
      //      keep-masked OR, then cross-group shfl OR-reduction
      u64 a0 = 0ull, a1 = 0ull;
#pragma unroll
      for (int rr = 0; rr < 16; ++rr) {
        int r = grp * 16 + rr;
        ulonglong2 v = *(const ulonglong2*)&buf[(size_t)r * WP + pr];
        u64 m = (u64)0 - ((keep >> r) & 1ull);
        a0 |= v.x & m;
        a1 |= v.y & m;
      }
      a0 |= shfl_xor_u64(a0, 16);
      a0 |= shfl_xor_u64(a0, 32);
      a1 |= shfl_xor_u64(a1, 16);
      a1 |= shfl_xor_u64(a1, 32);
      rm0 |= a0;
      rm1 |= a1;
      int stop = (base + 64 >= cnt) || (nk >= K);
      if (lane == 0) { s_ctl[par] = stop; s_ctl[2] = nk; }
    }
    __syncthreads();                           // staging done + stop/nk visible
    if (s_ctl[par]) break;                     // uniform exit
    base += 64;
    cur ^= 1;
  }
  __syncthreads();
  int nkf = s_ctl[2];
  for (int j = t; j < nkf; j += 256) {
    int i = s_keep[j];
    float4 bx = sboxes[(size_t)b * CAP_C + i];
    float sc = sscore[(size_t)b * CAP_C + i];
    float* row = out + ((size_t)b * K + j) * 6;
    row[0] = bx.x; row[1] = bx.y; row[2] = bx.z; row[3] = bx.w;
    row[4] = sc; row[5] = 1.0f;
  }
  for (int j = nkf + t; j < K; j += 256) {     // zero invalid tail rows
    float* row = out + ((size_t)b * K + j) * 6;
    row[0] = 0.f; row[1] = 0.f; row[2] = 0.f; row[3] = 0.f;
    row[4] = 0.f; row[5] = 0.f;
  }
}

extern "C" void kernel_launch(void* const* d_in, const int* in_sizes, int n_in,
                              void* d_out, int out_size, void* d_ws, size_t ws_size,
                              hipStream_t stream) {
  const float4* anchors = (const float4*)d_in[0];
  const float4* deltas = (const float4*)d_in[1];
  const float* obj = (const float*)d_in[2];
  const int* imh = (const int*)d_in[3];
  const int* imw = (const int*)d_in[4];
  int N = in_sizes[0] / 4;
  int B = in_sizes[2] / N;
  int K = out_size / (B * 6);
  if (K > KMAX) K = KMAX;

  // ws layout (alignment-descending)
  char* ws = (char*)d_ws;
  size_t off = 0;
  float4* sboxes = (float4*)(ws + off);           off += (size_t)B * CAP_C * 16;
  u64* mask = (u64*)(ws + off);                   off += (size_t)B * CAP_C * NW * 8;
  u64* cand = (u64*)(ws + off);                   off += (size_t)B * CAP_C * 8;
  unsigned* keys = (unsigned*)(ws + off);         off += (size_t)B * N * 4;
  unsigned* hist = (unsigned*)(ws + off);         off += (size_t)B * NBINS * 4;
  float* sscore = (float*)(ws + off);             off += (size_t)B * CAP_C * 4;
  unsigned* T_lo = (unsigned*)(ws + off);         off += (size_t)B * 4;
  off = (off + 255) & ~(size_t)255;               // cnt on its own lines
  unsigned* cnt = (unsigned*)(ws + off);          off += (size_t)B * CNT_STRIDE * 4;
  float* out = (float*)d_out;

  int nb = (N + 255) / 256;
  int P = (N + HE - 1) / HE;
  decode_kernel<<<nb, 256, 0, stream>>>(anchors, deltas, obj, imh, imw,
                                        keys, hist, cnt, N, B);
  hist_kernel<<<dim3(P, B), HB, 0, stream>>>(keys, hist, T_lo, cnt, N);
  compact_kernel<<<dim3(CPB, B), 1024, 0, stream>>>(keys, T_lo, cand, cnt, N);
  sort_kernel<<<B, 1024, 0, stream>>>(cand, cnt, anchors, deltas, imh, imw,
                                      sboxes, sscore, N);
  mask_kernel<<<dim3(CAP_C / MROWS, B), 256, 0, stream>>>(sboxes, mask);
  walk_kernel<<<B, 256, 0, stream>>>(mask, sboxes, sscore, cnt, out, K);
}

// Round 2
// 175.803 us; speedup vs baseline: 1.0520x; 1.0520x over previous
//
#include <hip/hip_runtime.h>
#include <cstdint>
#include <cstddef>

#define NBINS 32768         // 15-bit histogram of orderable score (u >> 17)
#define FINB 64u            // bin >= 64 <=> finite score (15-bit space)
#define CAP_C 2048          // candidate pool (pow2, = sort size)
#define NW (CAP_C / 64)     // 64-bit mask words per row = 32
#define TARGET 1792u        // threshold target (headroom to CAP_C)
#define KMAX 1008           // kept-list capacity
#define MROWS 16            // rows per mask block
#define HB 1024             // hist block threads
#define HE 32768            // keys per hist block (16-bit pack: counts <= HE < 65536)
#define CNT_STRIDE 64       // cnt[b*64]: 256B per counter, no shared lines
#define ARRIVE_OFF 16       // arrive counter at cnt[b*64+16]
#define CPB 64              // compact blocks per batch

typedef unsigned long long u64;

__device__ __forceinline__ unsigned orderable(float f) {
  unsigned b = __float_as_uint(f);
  return (b & 0x80000000u) ? ~b : (b | 0x80000000u);
}

__device__ __forceinline__ u64 shfl_xor_u64(u64 v, int m) {
  int lo = __shfl_xor((int)(unsigned)(v & 0xFFFFFFFFull), m, 64);
  int hi = __shfl_xor((int)(unsigned)(v >> 32), m, 64);
  return ((u64)(unsigned)hi << 32) | (u64)(unsigned)lo;
}

// async global->LDS, 16B per lane, dest = uniform base + lane*16 (m97 pattern)
__device__ __forceinline__ void gload_lds16(const u64* g, u64* l) {
  __builtin_amdgcn_global_load_lds(
      (const __attribute__((address_space(1))) unsigned int*)g,
      (__attribute__((address_space(3))) unsigned int*)l, 16, 0, 0);
}

// Pure streaming: computes keys only (boxes re-decoded later for the 2048
// winners). Also zero-fills hist + cnt/arrive lines (no separate init).
__global__ void decode_kernel(const float4* __restrict__ anchors,
                              const float4* __restrict__ deltas,
                              const float* __restrict__ obj,
                              const int* __restrict__ im_h_p,
                              const int* __restrict__ im_w_p,
                              unsigned* __restrict__ keys,
                              unsigned* __restrict__ hist,
                              unsigned* __restrict__ cnt,
                              int N, int B) {
#pragma clang fp contract(off)
  int n = blockIdx.x * blockDim.x + threadIdx.x;
  int stride = gridDim.x * blockDim.x;
  for (int j = n; j < B * NBINS; j += stride) hist[j] = 0u;
  for (int j = n; j < B * CNT_STRIDE; j += stride) cnt[j] = 0u;
  if (n >= N) return;
  float imw = (float)(*im_w_p);
  float imh = (float)(*im_h_p);
  float4 a = anchors[n];
  float aw = a.z - a.x;
  float ah = a.w - a.y;
  float acx = a.x + 0.5f * aw;
  float acy = a.y + 0.5f * ah;
  const float LOGM = 4.135166556742356f;  // log(1000/16) rounded to f32
  for (int b = 0; b < B; ++b) {
    size_t off = (size_t)b * N + n;
    float4 d = deltas[off];
    float dw = fminf(d.z, LOGM), dh = fminf(d.w, LOGM);
    float pcx = d.x * aw + acx;
    float pcy = d.y * ah + acy;
    float pw = expf(dw) * aw;
    float ph = expf(dh) * ah;
    float x1 = fminf(fmaxf(pcx - 0.5f * pw, 0.0f), imw);
    float y1 = fminf(fmaxf(pcy - 0.5f * ph, 0.0f), imh);
    float x2 = fminf(fmaxf(pcx + 0.5f * pw, 0.0f), imw);
    float y2 = fminf(fmaxf(pcy + 0.5f * ph, 0.0f), imh);
    float area = (x2 - x1) * (y2 - y1);
    float sc = (area > 1.0f) ? obj[off] : -__builtin_inff();
    keys[off] = orderable(sc);
  }
}

// LDS-privatized histogram, single pass + FUSED threshold (last-block-done).
__global__ void __launch_bounds__(HB) hist_kernel(const unsigned* __restrict__ keys,
                                                  unsigned* __restrict__ hist,
                                                  unsigned* __restrict__ T_lo,
                                                  unsigned* __restrict__ cnt,
                                                  int N) {
  __shared__ unsigned hl[NBINS / 2];  // 16384 uints = 64 KB (reused as scan scratch)
  int t = threadIdx.x, b = blockIdx.y;
  for (int i = t; i < NBINS / 2; i += HB) hl[i] = 0u;
  __syncthreads();
  const uint4* kb = (const uint4*)(keys + (size_t)b * N) + (size_t)blockIdx.x * (HE / 4);
  int lim = HE / 4;
  int rem4 = (N - blockIdx.x * HE) / 4;
  if (lim > rem4) lim = rem4;
  for (int i = t; i < lim; i += HB) {
    uint4 v = kb[i];
    unsigned b0 = v.x >> 17, b1 = v.y >> 17, b2 = v.z >> 17, b3 = v.w >> 17;
    atomicAdd(&hl[b0 >> 1], (b0 & 1u) ? 65536u : 1u);
    atomicAdd(&hl[b1 >> 1], (b1 & 1u) ? 65536u : 1u);
    atomicAdd(&hl[b2 >> 1], (b2 & 1u) ? 65536u : 1u);
    atomicAdd(&hl[b3 >> 1], (b3 & 1u) ? 65536u : 1u);
  }
  __syncthreads();
  unsigned* hg = hist + (size_t)b * NBINS;
  for (int i = t; i < NBINS / 2; i += HB) {
    unsigned v = hl[i];
    unsigned clo = v & 0xFFFFu, chi = v >> 16;
    if (clo) atomicAdd(&hg[2 * i], clo);
    if (chi) atomicAdd(&hg[2 * i + 1], chi);
  }
  __syncthreads();
  if (t == 0) {
    __threadfence();
    unsigned old = atomicAdd(&cnt[b * CNT_STRIDE + ARRIVE_OFF], 1u);
    hl[4096] = (old == gridDim.x - 1u) ? 1u : 0u;
  }
  __syncthreads();
  if (hl[4096] == 0u) return;
  // ---- fused threshold (this block arrived last for batch b) ----
  const int BPT = NBINS / 1024;  // 32 bins/thread, contiguous ownership
  unsigned mysum = 0;
  for (int k = 0; k < BPT; ++k) {
    unsigned bin = (unsigned)(t * BPT + k);
    if (bin >= FINB)
      mysum += __hip_atomic_load(&hg[bin], __ATOMIC_RELAXED, __HIP_MEMORY_SCOPE_AGENT);
  }
  if (t == 0) hl[2048] = 0xFFFFFFFFu;  // s_T slot
  hl[t] = mysum;                       // s_part = hl[0..1023]
  __syncthreads();
  for (int d = 1; d < 1024; d <<= 1) {  // inclusive suffix sum
    unsigned v = (t + d < 1024) ? hl[t + d] : 0u;
    __syncthreads();
    hl[t] += v;
    __syncthreads();
  }
  unsigned total = hl[0];
  unsigned target = (TARGET < total) ? TARGET : total;
  unsigned above = (t + 1 < 1024) ? hl[t + 1] : 0u;
  if (total > 0u && above < target && hl[t] >= target) {  // unique crossing thread
    unsigned c = above;
    for (int k = BPT - 1; k >= 0; --k) {
      unsigned bin = (unsigned)(t * BPT + k);
      if (bin < FINB) break;
      unsigned hv = __hip_atomic_load(&hg[bin], __ATOMIC_RELAXED, __HIP_MEMORY_SCOPE_AGENT);
      c += hv;
      if (c >= target) {
        unsigned T = bin;
        if (c > CAP_C && (c - hv) > 0u) T = bin + 1u;  // never overflow CAP_C
        hl[2048] = T;
        break;
      }
    }
  }
  __syncthreads();
  if (t == 0) T_lo[b] = (total == 0u) ? 0xFFFFFFFFu : hl[2048];
}

// compact (full-GPU grid, block-aggregated)
__global__ void __launch_bounds__(1024) compact_kernel(const unsigned* __restrict__ keys,
                                                       const unsigned* __restrict__ T_lo,
                                                       u64* __restrict__ cand,
                                                       unsigned* __restrict__ cnt, int N) {
  __shared__ u64 s_w[4096];  // 32 KB winner staging (total/batch <= ~2048)
  __shared__ unsigned s_n, s_base;
  int b = blockIdx.y, t = threadIdx.x;
  if (t == 0) s_n = 0u;
  __syncthreads();
  unsigned T = T_lo[b];
  int slice4 = N / 4 / CPB;  // uint4s per block (N=262144: 1024 -> 1/thread)
  const uint4* k4 = (const uint4*)(keys + (size_t)b * N) + (size_t)blockIdx.x * slice4;
  for (int i = t; i < slice4; i += 1024) {
    uint4 v = k4[i];
    int bi = (blockIdx.x * slice4 + i) * 4;
    if ((v.x >> 17) >= T) { unsigned p = atomicAdd(&s_n, 1u); if (p < 4096u) s_w[p] = ((u64)v.x << 32) | (unsigned)(~(bi + 0)); }
    if ((v.y >> 17) >= T) { unsigned p = atomicAdd(&s_n, 1u); if (p < 4096u) s_w[p] = ((u64)v.y << 32) | (unsigned)(~(bi + 1)); }
    if ((v.z >> 17) >= T) { unsigned p = atomicAdd(&s_n, 1u); if (p < 4096u) s_w[p] = ((u64)v.z << 32) | (unsigned)(~(bi + 2)); }
    if ((v.w >> 17) >= T) { unsigned p = atomicAdd(&s_n, 1u); if (p < 4096u) s_w[p] = ((u64)v.w << 32) | (unsigned)(~(bi + 3)); }
  }
  __syncthreads();
  unsigned n = s_n < 4096u ? s_n : 4096u;
  if (t == 0) s_base = (n > 0u) ? atomicAdd(&cnt[b * CNT_STRIDE], n) : 0u;
  __syncthreads();
  unsigned gb = s_base;
  for (unsigned j = t; j < n; j += 1024) {
    unsigned p = gb + j;
    if (p < CAP_C) cand[(size_t)b * CAP_C + p] = s_w[j];
  }
}

// One block per batch: bitonic sort CAP_C keys descending, then gather sorted
// boxes by RE-DECODING the winners (bit-exact vs decode, fp contract off).
__global__ void __launch_bounds__(1024) sort_kernel(const u64* __restrict__ cand,
                                                    const unsigned* __restrict__ cntp,
                                                    const float4* __restrict__ anchors,
                                                    const float4* __restrict__ deltas,
                                                    const int* __restrict__ im_h_p,
                                                    const int* __restrict__ im_w_p,
                                                    float4* __restrict__ sboxes,
                                                    float* __restrict__ sscore,
                                                    int N) {
#pragma clang fp contract(off)
  __shared__ u64 sk[CAP_C];  // 16 KB
  int b = blockIdx.x, t = threadIdx.x;
  int cnt = (int)cntp[b * CNT_STRIDE];
  if (cnt > CAP_C) cnt = CAP_C;
  for (int i = t; i < CAP_C; i += 1024)
    sk[i] = (i < cnt) ? cand[(size_t)b * CAP_C + i] : 0ull;  // pad sinks to end
  __syncthreads();
  for (unsigned kk = 2; kk <= CAP_C; kk <<= 1) {
    for (unsigned j = kk >> 1; j >= 1u; j >>= 1) {
      if (j >= 64u) __syncthreads();  // inter-wave phases only
      unsigned pid = (unsigned)t;     // exactly CAP_C/2 pairs
      unsigned i = ((pid & ~(j - 1u)) << 1) | (pid & (j - 1u));
      unsigned p = i | j;
      u64 va = sk[i], vb = sk[p];
      bool up = ((i & kk) == 0u);
      bool sw = up ? (va < vb) : (va > vb);
      if (sw) { sk[i] = vb; sk[p] = va; }
    }
  }
  __syncthreads();
  float imw = (float)(*im_w_p);
  float imh = (float)(*im_h_p);
  const float LOGM = 4.135166556742356f;
  for (int i = t; i < CAP_C; i += 1024) {
    u64 key = sk[i];
    float4 bx = make_float4(0.f, 0.f, 0.f, 0.f);
    float sc = -__builtin_inff();
    if (i < cnt) {
      unsigned idx = ~(unsigned)(key & 0xFFFFFFFFull);
      float4 a = anchors[idx];
      float4 d = deltas[(size_t)b * N + idx];
      float aw = a.z - a.x;
      float ah = a.w - a.y;
      float acx = a.x + 0.5f * aw;
      float acy = a.y + 0.5f * ah;
      float dw = fminf(d.z, LOGM), dh = fminf(d.w, LOGM);
      float pcx = d.x * aw + acx;
      float pcy = d.y * ah + acy;
      float pw = expf(dw) * aw;
      float ph = expf(dh) * ah;
      bx.x = fminf(fmaxf(pcx - 0.5f * pw, 0.0f), imw);
      bx.y = fminf(fmaxf(pcy - 0.5f * ph, 0.0f), imh);
      bx.z = fminf(fmaxf(pcx + 0.5f * pw, 0.0f), imw);
      bx.w = fminf(fmaxf(pcy + 0.5f * ph, 0.0f), imh);
      unsigned u = (unsigned)(key >> 32);
      unsigned sb2 = (u & 0x80000000u) ? (u ^ 0x80000000u) : ~u;
      sc = __uint_as_float(sb2);
    }
    sboxes[(size_t)b * CAP_C + i] = bx;
    sscore[(size_t)b * CAP_C + i] = sc;
  }
}

// Pairwise suppression masks — UPPER TRIANGLE ONLY (chunk >= row>>6).
__global__ void __launch_bounds__(256) mask_kernel(const float4* __restrict__ sboxes,
                                                   u64* __restrict__ mask) {
#pragma clang fp contract(off)
  __shared__ float4 sb[CAP_C];  // 32 KB
  int b = blockIdx.y, t = threadIdx.x;
  int wave = t >> 6, lane = t & 63;
  const float4* src = sboxes + (size_t)b * CAP_C;
  for (int i = t; i < CAP_C; i += 256) sb[i] = src[i];
  __syncthreads();
  for (int r = 0; r < MROWS; ++r) {
    int row = blockIdx.x * MROWS + r;
    int c0 = row >> 6;                         // first live chunk (diag block)
    float4 rb = sb[row];                       // broadcast read
    float ra = (rb.z - rb.x) * (rb.w - rb.y);  // picked-box area (barea)
    for (int chunk = wave; chunk < NW; chunk += 4) {
      if (chunk < c0) continue;                // wave-uniform skip (dead words)
      float4 cb = sb[chunk * 64 + lane];
      float ix1 = fmaxf(rb.x, cb.x), iy1 = fmaxf(rb.y, cb.y);
      float ix2 = fminf(rb.z, cb.z), iy2 = fminf(rb.w, cb.w);
      float inter = fmaxf(ix2 - ix1, 0.0f) * fmaxf(iy2 - iy1, 0.0f);
      float ca = (cb.z - cb.x) * (cb.w - cb.y);
      float iou = inter / (ra + ca - inter + 1e-9f);
      u64 bal = __ballot(iou > 0.7f);
      if (lane == 0)
        mask[((size_t)b * CAP_C + row) * NW + chunk] = bal;
    }
  }
}

// ---- Walk v9: producer/consumer pipeline, async global_load_lds staging.
// LDS tile is LINEAR [64][NW] (global_load_lds needs base+lane*16 dests).
// Staging is predicated to live columns only (col >= tile index): dead
// columns are unwritten mask memory (harness poison, guaranteed L2-cold);
// their stale LDS contents only OR into removed-words already consumed.
// All staging loads issue async, drained once by __syncthreads' vmcnt(0).
__global__ void __launch_bounds__(256, 1) walk_kernel(const u64* __restrict__ mask,
                                                      const float4* __restrict__ sboxes,
                                                      const float* __restrict__ sscore,
                                                      const unsigned* __restrict__ cntp,
                                                      float* __restrict__ out, int K) {
  __shared__ u64 s_buf[2][64 * NW];   // 2 x 16 KB staged tiles (linear)
  __shared__ int s_keep[KMAX];
  __shared__ int s_ctl[4];            // [tt&1]: stop flag, [2]: nk
  const int b = blockIdx.x;
  const int t = threadIdx.x;
  const int wave = t >> 6, lane = t & 63;
  const u64* M = mask + (size_t)b * CAP_C * NW;
  int cnt = (int)cntp[b * CNT_STRIDE];
  if (cnt > CAP_C) cnt = CAP_C;
  const u64 lane_above = (lane == 63) ? 0ull : (~0ull << (lane + 1));
  const int colp1 = ((lane & 15) * 2) + 1;  // last column of this lane's 16B pair

  // prologue: all 4 waves stage tile 0 (16 chunks of 1 KB, all columns live)
  for (int k = 0; k < 4; ++k) {
    int c = wave + 4 * k;
    gload_lds16(M + c * 128 + lane * 2, &s_buf[0][c * 128]);
  }
  if (t == 0) { s_ctl[0] = 0; s_ctl[1] = 0; s_ctl[2] = 0; }
  __syncthreads();

  u64 rm0 = 0ull, rm1 = 0ull;  // removed words (2p, 2p+1), p = lane&15, dup x4
  int nk = 0;                  // wave0-maintained keep count
  int base = 0;
  int cur = 0;
  const int pr = (lane & 15) * 2;  // word index of this lane's pair
  const int grp = lane >> 4;       // 16-row group owned in apply

  for (int tt = 0; tt < CAP_C / 64; ++tt) {
    int par = tt & 1;
    if (wave != 0) {
      // ---- producer: async-stage tile tt+1 (live columns only)
      int nt = tt + 1;
      if (nt > CAP_C / 64 - 1) nt = CAP_C / 64 - 1;
      const u64* src = M + (size_t)nt * (64 * NW);  // tiles are contiguous 16 KB
      u64* dst = s_buf[cur ^ 1];
      for (int k = 0; k < 6; ++k) {
        int c = (wave - 1) + 3 * k;  // wave1: 0,3,..15; wave2: 1,..13; wave3: 2,..14
        if (c < 16 && colp1 >= nt)   // skip dead (unwritten/poison) columns
          gload_lds16(src + c * 128 + lane * 2, dst + c * 128);
      }
    } else {
      // ---- consumer (wave 0): resolve tile tt from staged buffer
      const u64* buf = s_buf[cur];
      int tw = base >> 6;                      // 0..31
      u64 D = buf[(size_t)lane * NW + tw];     // lane j = row j's tile-diag word
      u64 rmw = (tw & 1) ? rm1 : rm0;          // uniform pair-half select
      unsigned rlo = __builtin_amdgcn_readlane((unsigned)(rmw & 0xFFFFFFFFull), tw >> 1);
      unsigned rhi = __builtin_amdgcn_readlane((unsigned)(rmw >> 32), tw >> 1);
      u64 in_rm = ((u64)rhi << 32) | (u64)rlo;
      int rem = cnt - base;
      u64 valid = (rem >= 64) ? ~0ull : ((rem <= 0) ? 0ull : ((1ull << rem) - 1ull));
      u64 pend = (~in_rm) & valid;
      u64 keep = 0ull;
      while (pend != 0ull) {                   // O(#suppressing keeps) trips
        bool cond = ((pend >> lane) & 1ull) && ((D & pend & lane_above) != 0ull);
        u64 bal = __ballot((int)cond);
        if (bal == 0ull) { keep |= pend; break; }
        int f = __builtin_ctzll(bal);
        u64 beq = (2ull << f) - 1ull;          // bits <= f (f=63 wraps to ~0)
        keep |= pend & beq;
        unsigned dlo = __builtin_amdgcn_readlane((unsigned)(D & 0xFFFFFFFFull), f);
        unsigned dhi = __builtin_amdgcn_readlane((unsigned)(D >> 32), f);
        u64 rowf = ((u64)dhi << 32) | (u64)dlo;
        pend &= ~beq;
        pend &= ~rowf;
      }
      int cap = K - nk;
      int kc = __popcll(keep);
      if (kc > cap) {                          // exact greedy K-cutoff
        bool mine = ((keep >> lane) & 1ull) &&
                    (__popcll(keep & ((1ull << lane) - 1ull)) < cap);
        keep = __ballot((int)mine);
        kc = cap;
      }
      if ((keep >> lane) & 1ull)
        s_keep[nk + __popcll(keep & ((1ull << lane) - 1ull))] = base + lane;
      nk += kc;
      // ---- apply: 16 x ds_read_b128 (word-pair per lane, 16 rows per group),
      //      keep-masked OR, then cross-group shfl OR-reduction
      u64 a0 = 0ull, a1 = 0ull;
#pragma unroll
      for (int rr = 0; rr < 16; ++rr) {
        int r = grp * 16 + rr;
        ulonglong2 v = *(const ulonglong2*)&buf[(size_t)r * NW + pr];
        u64 m = (u64)0 - ((keep >> r) & 1ull);
        a0 |= v.x & m;
        a1 |= v.y & m;
      }
      a0 |= shfl_xor_u64(a0, 16);
      a0 |= shfl_xor_u64(a0, 32);
      a1 |= shfl_xor_u64(a1, 16);
      a1 |= shfl_xor_u64(a1, 32);
      rm0 |= a0;
      rm1 |= a1;
      int stop = (base + 64 >= cnt) || (nk >= K);
      if (lane == 0) { s_ctl[par] = stop; s_ctl[2] = nk; }
    }
    __syncthreads();                           // staging drained + stop/nk visible
    if (s_ctl[par]) break;                     // uniform exit
    base += 64;
    cur ^= 1;
  }
  __syncthreads();
  int nkf = s_ctl[2];
  for (int j = t; j < nkf; j += 256) {
    int i = s_keep[j];
    float4 bx = sboxes[(size_t)b * CAP_C + i];
    float sc = sscore[(size_t)b * CAP_C + i];
    float* row = out + ((size_t)b * K + j) * 6;
    row[0] = bx.x; row[1] = bx.y; row[2] = bx.z; row[3] = bx.w;
    row[4] = sc; row[5] = 1.0f;
  }
  for (int j = nkf + t; j < K; j += 256) {     // zero invalid tail rows
    float* row = out + ((size_t)b * K + j) * 6;
    row[0] = 0.f; row[1] = 0.f; row[2] = 0.f; row[3] = 0.f;
    row[4] = 0.f; row[5] = 0.f;
  }
}

extern "C" void kernel_launch(void* const* d_in, const int* in_sizes, int n_in,
                              void* d_out, int out_size, void* d_ws, size_t ws_size,
                              hipStream_t stream) {
  const float4* anchors = (const float4*)d_in[0];
  const float4* deltas = (const float4*)d_in[1];
  const float* obj = (const float*)d_in[2];
  const int* imh = (const int*)d_in[3];
  const int* imw = (const int*)d_in[4];
  int N = in_sizes[0] / 4;
  int B = in_sizes[2] / N;
  int K = out_size / (B * 6);
  if (K > KMAX) K = KMAX;

  // ws layout (alignment-descending)
  char* ws = (char*)d_ws;
  size_t off = 0;
  float4* sboxes = (float4*)(ws + off);           off += (size_t)B * CAP_C * 16;
  u64* mask = (u64*)(ws + off);                   off += (size_t)B * CAP_C * NW * 8;
  u64* cand = (u64*)(ws + off);                   off += (size_t)B * CAP_C * 8;
  unsigned* keys = (unsigned*)(ws + off);         off += (size_t)B * N * 4;
  unsigned* hist = (unsigned*)(ws + off);         off += (size_t)B * NBINS * 4;
  float* sscore = (float*)(ws + off);             off += (size_t)B * CAP_C * 4;
  unsigned* T_lo = (unsigned*)(ws + off);         off += (size_t)B * 4;
  off = (off + 255) & ~(size_t)255;               // cnt on its own lines
  unsigned* cnt = (unsigned*)(ws + off);          off += (size_t)B * CNT_STRIDE * 4;
  float* out = (float*)d_out;

  int nb = (N + 255) / 256;
  int P = (N + HE - 1) / HE;
  decode_kernel<<<nb, 256, 0, stream>>>(anchors, deltas, obj, imh, imw,
                                        keys, hist, cnt, N, B);
  hist_kernel<<<dim3(P, B), HB, 0, stream>>>(keys, hist, T_lo, cnt, N);
  compact_kernel<<<dim3(CPB, B), 1024, 0, stream>>>(keys, T_lo, cand, cnt, N);
  sort_kernel<<<B, 1024, 0, stream>>>(cand, cnt, anchors, deltas, imh, imw,
                                      sboxes, sscore, N);
  mask_kernel<<<dim3(CAP_C / MROWS, B), 256, 0, stream>>>(sboxes, mask);
  walk_kernel<<<B, 256, 0, stream>>>(mask, sboxes, sscore, cnt, out, K);
}